// Round 13
// baseline (208.163 us; speedup 1.0000x reference)
//
#include <hip/hip_runtime.h>

// VQ quantizer: z [8,8,16,64,64] f32, codebook [512,8] f32
// outputs concat: z_q_st (4194304 f32) | vq_loss (1 f32) | idx (524288 f32-valued)
//
// R13 = R12 (59.9us) minus two of the three block barriers:
//  - barrier #2 (pass2 -> phase C) replaced by s_waitcnt lgkmcnt(0): ccnt/clist
//    for a wave's 64 points is wave-private (writers & readers in same wave),
//    so only same-wave LDS completion is needed, not a block rendezvous.
//  - barrier #3 (loss) removed: per-wave atomicAdd of the partial (loss tol 2%).
// 8 waves/block no longer rendezvous after the skewed pass2 -> stall absorbed.
// Validated bit-exact pipeline (absmax 0, R6-R12): split-bf16 MFMA filter,
// eps-threshold candidate collection, np-exact rescue. Outputs 0/2 unchanged.

#define NPTS      524288      // 8*16*64*64
#define KCODES    512
#define DDIM      8
#define CH_STRIDE 65536       // T*H*W
#define B_STRIDE  524288      // D*T*H*W
#define BLK       512
#define NWAVES    8
#define NTILES    32          // 512 codes / 16
#define CMAX      4
#define FLT_BIG   3.402823466e+38f

typedef short bf8 __attribute__((ext_vector_type(8)));   // 8 bf16 (4 VGPRs)
typedef float f4  __attribute__((ext_vector_type(4)));   // fp32 accum

__device__ __forceinline__ unsigned short f2bf(float f) {   // RNE f32->bf16
    unsigned u = __float_as_uint(f);
    unsigned r = u + 0x7fffu + ((u >> 16) & 1u);
    return (unsigned short)(r >> 16);
}
__device__ __forceinline__ float bf2f(unsigned short h) {
    return __uint_as_float(((unsigned)h) << 16);
}

// numpy pairwise-sum tree for n=8 (validated absmax 0, R1-R12)
__device__ __forceinline__ float np_sumsq8(const float* x) {
    float p0 = __fmul_rn(x[0], x[0]);
    float p1 = __fmul_rn(x[1], x[1]);
    float p2 = __fmul_rn(x[2], x[2]);
    float p3 = __fmul_rn(x[3], x[3]);
    float p4 = __fmul_rn(x[4], x[4]);
    float p5 = __fmul_rn(x[5], x[5]);
    float p6 = __fmul_rn(x[6], x[6]);
    float p7 = __fmul_rn(x[7], x[7]);
    return __fadd_rn(__fadd_rn(__fadd_rn(p0, p1), __fadd_rn(p2, p3)),
                     __fadd_rn(__fadd_rn(p4, p5), __fadd_rn(p6, p7)));
}

// np-exact distance (identical rounding chain, absmax-0 validated)
__device__ __forceinline__ float np_dist(const float* __restrict__ cb,
                                         const float* __restrict__ e2f,
                                         int k, const float* zv, float z2) {
    const float* c = cb + (size_t)k * DDIM;
    float ze = 0.0f;
    #pragma unroll
    for (int j = 0; j < DDIM; ++j) ze = __fmaf_rn(zv[j], c[j], ze);
    return __fmaf_rn(-2.0f, ze, __fadd_rn(z2, e2f[k]));
}

// prep (unchanged since R6, validated): e2f table + B fragments
// B[k][n]: n=lane&15 (code), k=(lane>>4)*8+j. quad0: eh, quad1: el, quad2: eh,
// quad3: {e2h, e2l, 0x6}.
__global__ void prep(const float* __restrict__ cb, float* __restrict__ e2f,
                     unsigned short* __restrict__ wsB, float* __restrict__ out_loss) {
    const int tid = blockIdx.x * 256 + threadIdx.x;
    if (tid == 0) *out_loss = 0.0f;
    const int t    = tid >> 6;
    const int lane = tid & 63;
    const int quad = lane >> 4;
    const int colc = lane & 15;
    const int n    = t * 16 + colc;
    float row[DDIM];
    #pragma unroll
    for (int j = 0; j < DDIM; ++j) row[j] = cb[n * DDIM + j];
    const float e2 = np_sumsq8(row);
    if (quad == 3) e2f[n] = e2;

    unsigned short sh[8];
    #pragma unroll
    for (int j = 0; j < 8; ++j) {
        const unsigned short eh = f2bf(row[j]);
        const unsigned short el = f2bf(__fsub_rn(row[j], bf2f(eh)));
        sh[j] = (quad == 1) ? el : eh;
    }
    if (quad == 3) {
        const unsigned short e2h = f2bf(e2);
        const unsigned short e2l = f2bf(__fsub_rn(e2, bf2f(e2h)));
        sh[0] = e2h; sh[1] = e2l;
        #pragma unroll
        for (int j = 2; j < 8; ++j) sh[j] = 0;
    }
    unsigned short* dst = wsB + (size_t)(t * 64 + lane) * 8;
    #pragma unroll
    for (int j = 0; j < 8; ++j) dst[j] = sh[j];
}

__global__ __launch_bounds__(BLK, 4) void vq_main(
    const float* __restrict__ z, const float* __restrict__ cb,
    const float* __restrict__ e2f, const unsigned short* __restrict__ wsB,
    float* __restrict__ out_zq, float* __restrict__ out_loss,
    float* __restrict__ out_idx)
{
    __shared__ unsigned short ldsB[NTILES * 64 * 8];   // 32 KB
    __shared__ int            ccnt[BLK];               // 2 KB
    __shared__ unsigned short clist[BLK][CMAX];        // 4 KB

    const int tid  = threadIdx.x;
    const int wave = tid >> 6;
    const int lane = tid & 63;
    const int quad = lane >> 4;
    const int col  = lane & 15;

    // stage B fragments global -> LDS (32 KB, coalesced uint4, 4 iters @512thr)
    {
        const uint4* src = (const uint4*)wsB;
        uint4* dst = (uint4*)ldsB;
        #pragma unroll
        for (int q = 0; q < 4; ++q)
            dst[tid + q * BLK] = src[tid + q * BLK];
    }
    ccnt[tid] = 0;

    // lane owns point n: fully coalesced loads
    const int n = blockIdx.x * BLK + tid;
    const int b = n >> 16;
    const int s = n & 65535;
    const float* zp = z + (size_t)b * B_STRIDE + s;
    float zv[DDIM];
    #pragma unroll
    for (int j = 0; j < DDIM; ++j) zv[j] = zp[(size_t)j * CH_STRIDE];
    const float z2 = np_sumsq8(zv);

    // wave-wide z2 max -> eps (validated constants)
    float zmax = z2;
    #pragma unroll
    for (int mk = 1; mk <= 32; mk <<= 1) zmax = fmaxf(zmax, __shfl_xor(zmax, mk, 64));
    const float eps = zmax * 6e-7f + 3e-6f;

    // pre-pack own point's A-material: lo16 = bf16(-2*zh), hi16 = bf16(-2*zl)
    unsigned pkz[8];
    #pragma unroll
    for (int j = 0; j < 8; ++j) {
        const unsigned short hh = f2bf(zv[j]);
        const float zh = bf2f(hh);
        const float zl = __fsub_rn(zv[j], zh);        // exact
        const unsigned short ah = f2bf(-2.0f * zh);   // exact
        const unsigned short al = f2bf(-2.0f * zl);
        pkz[j] = (unsigned)ah | ((unsigned)al << 16);
    }

    // afrag_q at lane (col,quad): A[m=col][k=quad*8+j] from owner lane q*16+col.
    // quad0/1: -2zh, quad2: -2zl, quad3: {1,1,0..} (validated)
    bf8 af0, af1, af2, af3;
#define MK_AFRAG(AF, Q)                                                        \
    {                                                                          \
        const int srcl = (Q)*16 + col;                                         \
        _Pragma("unroll")                                                      \
        for (int j = 0; j < 8; ++j) {                                          \
            const unsigned w = (unsigned)__shfl((int)pkz[j], srcl, 64);        \
            const unsigned us = (quad == 2) ? (w >> 16) : (w & 0xFFFFu);       \
            AF[j] = (short)us;                                                 \
        }                                                                      \
        if (quad == 3) AF = (bf8){(short)0x3F80, (short)0x3F80, 0, 0, 0, 0, 0, 0}; \
    }
    MK_AFRAG(af0, 0) MK_AFRAG(af1, 1) MK_AFRAG(af2, 2) MK_AFRAG(af3, 3)

    __syncthreads();   // ldsB staged by all waves -> needed (kept)

    const bf8* __restrict__ Bp = (const bf8*)ldsB;   // ds_read_b128 per tile

    // ---- pass 1: approx min per point (4 ptiles x 4 regs) ----
    f4 mn0 = (f4){FLT_BIG, FLT_BIG, FLT_BIG, FLT_BIG};
    f4 mn1 = mn0, mn2 = mn0, mn3 = mn0;
    #pragma unroll 4
    for (int t = 0; t < NTILES; ++t) {
        const bf8 bfrag = Bp[t * 64 + lane];
        f4 zero = (f4){0.0f, 0.0f, 0.0f, 0.0f};
        const f4 a0 = __builtin_amdgcn_mfma_f32_16x16x32_bf16(af0, bfrag, zero, 0, 0, 0);
        const f4 a1 = __builtin_amdgcn_mfma_f32_16x16x32_bf16(af1, bfrag, zero, 0, 0, 0);
        const f4 a2 = __builtin_amdgcn_mfma_f32_16x16x32_bf16(af2, bfrag, zero, 0, 0, 0);
        const f4 a3 = __builtin_amdgcn_mfma_f32_16x16x32_bf16(af3, bfrag, zero, 0, 0, 0);
        #pragma unroll
        for (int r = 0; r < 4; ++r) {
            mn0[r] = fminf(mn0[r], a0[r]); mn1[r] = fminf(mn1[r], a1[r]);
            mn2[r] = fminf(mn2[r], a2[r]); mn3[r] = fminf(mn3[r], a3[r]);
        }
    }
    // min across the 16 cols (xor bits 0..3), then add eps -> thresholds
    #pragma unroll
    for (int mk = 1; mk <= 8; mk <<= 1) {
        #pragma unroll
        for (int r = 0; r < 4; ++r) {
            mn0[r] = fminf(mn0[r], __shfl_xor(mn0[r], mk, 64));
            mn1[r] = fminf(mn1[r], __shfl_xor(mn1[r], mk, 64));
            mn2[r] = fminf(mn2[r], __shfl_xor(mn2[r], mk, 64));
            mn3[r] = fminf(mn3[r], __shfl_xor(mn3[r], mk, 64));
        }
    }
    #pragma unroll
    for (int r = 0; r < 4; ++r) {
        mn0[r] += eps; mn1[r] += eps; mn2[r] += eps; mn3[r] += eps;
    }

    // ---- pass 2: identical accs; predicated push (rarely taken) ----
    // C layout: point-in-block = wave*64 + Q*16 + quad*4 + r, code = t*16 + col
    const int pbase = wave * 64 + quad * 4;
    #pragma unroll 4
    for (int t = 0; t < NTILES; ++t) {
        const bf8 bfrag = Bp[t * 64 + lane];
        f4 zero = (f4){0.0f, 0.0f, 0.0f, 0.0f};
        const f4 a0 = __builtin_amdgcn_mfma_f32_16x16x32_bf16(af0, bfrag, zero, 0, 0, 0);
        const f4 a1 = __builtin_amdgcn_mfma_f32_16x16x32_bf16(af1, bfrag, zero, 0, 0, 0);
        const f4 a2 = __builtin_amdgcn_mfma_f32_16x16x32_bf16(af2, bfrag, zero, 0, 0, 0);
        const f4 a3 = __builtin_amdgcn_mfma_f32_16x16x32_bf16(af3, bfrag, zero, 0, 0, 0);
        const unsigned short code = (unsigned short)(t * 16 + col);
#define PUSH(AQ, MQ, Q)                                                        \
    {                                                                          \
        const bool c0 = AQ[0] <= MQ[0], c1 = AQ[1] <= MQ[1];                   \
        const bool c2 = AQ[2] <= MQ[2], c3 = AQ[3] <= MQ[3];                   \
        if (c0 | c1 | c2 | c3) {                                               \
            const int pt = pbase + (Q)*16;                                     \
            if (c0) { int p = atomicAdd(&ccnt[pt + 0], 1); if (p < CMAX) clist[pt + 0][p] = code; } \
            if (c1) { int p = atomicAdd(&ccnt[pt + 1], 1); if (p < CMAX) clist[pt + 1][p] = code; } \
            if (c2) { int p = atomicAdd(&ccnt[pt + 2], 1); if (p < CMAX) clist[pt + 2][p] = code; } \
            if (c3) { int p = atomicAdd(&ccnt[pt + 3], 1); if (p < CMAX) clist[pt + 3][p] = code; } \
        }                                                                      \
    }
        PUSH(a0, mn0, 0) PUSH(a1, mn1, 1) PUSH(a2, mn2, 2) PUSH(a3, mn3, 3)
    }

    // ccnt/clist for this wave's 64 points are written ONLY by this wave's lanes
    // and read ONLY by this wave's lanes -> no block barrier needed; just drain
    // this wave's outstanding LDS ops (writes + atomics) before the reads.
    asm volatile("s_waitcnt lgkmcnt(0)" ::: "memory");

    // ---- phase C: every lane resolves its own point np-exactly ----
    const int cnt = ccnt[tid];
    int bidx;
    if (cnt == 1) {
        // eps guarantee: candidate set contains np's argmin; singleton => done
        bidx = clist[tid][0];
    } else if (cnt <= CMAX) {
        float best = FLT_BIG; bidx = 0;
        for (int i = 0; i < cnt; ++i) {
            const int k = clist[tid][i];
            const float d = np_dist(cb, e2f, k, zv, z2);
            // order-independent np first-min
            if (d < best || (d == best && k < bidx)) { best = d; bidx = k; }
        }
    } else {  // overflow fallback: full exact scan (correctness net)
        float best = FLT_BIG; bidx = 0;
        for (int k = 0; k < KCODES; ++k) {
            const float d = np_dist(cb, e2f, k, zv, z2);
            if (d < best) { best = d; bidx = k; }
        }
    }
    out_idx[n] = (float)bidx;

    const float* cw = cb + (size_t)bidx * DDIM;
    float* op = out_zq + (size_t)b * B_STRIDE + s;
    float lsum = 0.0f;
    #pragma unroll
    for (int j = 0; j < DDIM; ++j) {
        const float zq = cw[j];
        const float t  = __fsub_rn(zq, zv[j]);            // np: z_q - z
        op[(size_t)j * CH_STRIDE] = __fadd_rn(zv[j], t);  // np: z + (z_q - z)
        lsum = __fmaf_rn(t, t, lsum);                     // loss (2% tol)
    }

    // loss: wave butterfly -> one atomic per wave (no block barrier)
    #pragma unroll
    for (int off = 32; off > 0; off >>= 1) lsum += __shfl_down(lsum, off, 64);
    if (lane == 0) {
        // vq_loss = codebk + BETA*commit = 1.25 * mean((z_q - z)^2)
        atomicAdd(out_loss, lsum * (1.25f / 4194304.0f));
    }
}

extern "C" void kernel_launch(void* const* d_in, const int* in_sizes, int n_in,
                              void* d_out, int out_size, void* d_ws, size_t ws_size,
                              hipStream_t stream) {
    const float* z  = (const float*)d_in[0];
    const float* cb = (const float*)d_in[1];
    float* out      = (float*)d_out;
    float* out_zq   = out;                    // 4194304 elems
    float* out_loss = out + 4194304;          // 1 elem
    float* out_idx  = out + 4194305;          // 524288 elems (as float values)
    float* e2f            = (float*)d_ws;                           // 512 f32
    unsigned short* wsB   = (unsigned short*)((char*)d_ws + 2048);  // 32KB frags

    prep<<<8, 256, 0, stream>>>(cb, e2f, wsB, out_loss);
    vq_main<<<NPTS / BLK, BLK, 0, stream>>>(z, cb, e2f, wsB,
                                            out_zq, out_loss, out_idx);
}

// Round 14
// 119.494 us; speedup vs baseline: 1.7420x; 1.7420x over previous
//
#include <hip/hip_runtime.h>

// VQ quantizer: z [8,8,16,64,64] f32, codebook [512,8] f32
// outputs concat: z_q_st (4194304 f32) | vq_loss (1 f32) | idx (524288 f32-valued)
//
// R14 = R12 (59.9us) + ONLY the barrier-#2 removal from R13:
//  - pass2 -> phase C: ccnt/clist for a wave's 64 points is wave-private
//    (writers & readers in same wave) -> s_waitcnt lgkmcnt(0), no block barrier.
//  - loss path REVERTED to R12: wave butterfly -> LDS wsum -> __syncthreads ->
//    ONE global atomic per block (1024 total). R13's per-wave atomics (8192
//    same-address RMWs, ~26cyc each serialized) were the 90us regression.
// Validated bit-exact pipeline (absmax 0, R6-R13): split-bf16 MFMA filter,
// eps-threshold candidate collection, np-exact rescue. Outputs 0/2 unchanged.

#define NPTS      524288      // 8*16*64*64
#define KCODES    512
#define DDIM      8
#define CH_STRIDE 65536       // T*H*W
#define B_STRIDE  524288      // D*T*H*W
#define BLK       512
#define NWAVES    8
#define NTILES    32          // 512 codes / 16
#define CMAX      4
#define FLT_BIG   3.402823466e+38f

typedef short bf8 __attribute__((ext_vector_type(8)));   // 8 bf16 (4 VGPRs)
typedef float f4  __attribute__((ext_vector_type(4)));   // fp32 accum

__device__ __forceinline__ unsigned short f2bf(float f) {   // RNE f32->bf16
    unsigned u = __float_as_uint(f);
    unsigned r = u + 0x7fffu + ((u >> 16) & 1u);
    return (unsigned short)(r >> 16);
}
__device__ __forceinline__ float bf2f(unsigned short h) {
    return __uint_as_float(((unsigned)h) << 16);
}

// numpy pairwise-sum tree for n=8 (validated absmax 0, R1-R13)
__device__ __forceinline__ float np_sumsq8(const float* x) {
    float p0 = __fmul_rn(x[0], x[0]);
    float p1 = __fmul_rn(x[1], x[1]);
    float p2 = __fmul_rn(x[2], x[2]);
    float p3 = __fmul_rn(x[3], x[3]);
    float p4 = __fmul_rn(x[4], x[4]);
    float p5 = __fmul_rn(x[5], x[5]);
    float p6 = __fmul_rn(x[6], x[6]);
    float p7 = __fmul_rn(x[7], x[7]);
    return __fadd_rn(__fadd_rn(__fadd_rn(p0, p1), __fadd_rn(p2, p3)),
                     __fadd_rn(__fadd_rn(p4, p5), __fadd_rn(p6, p7)));
}

// np-exact distance (identical rounding chain, absmax-0 validated)
__device__ __forceinline__ float np_dist(const float* __restrict__ cb,
                                         const float* __restrict__ e2f,
                                         int k, const float* zv, float z2) {
    const float* c = cb + (size_t)k * DDIM;
    float ze = 0.0f;
    #pragma unroll
    for (int j = 0; j < DDIM; ++j) ze = __fmaf_rn(zv[j], c[j], ze);
    return __fmaf_rn(-2.0f, ze, __fadd_rn(z2, e2f[k]));
}

// prep (unchanged since R6, validated): e2f table + B fragments
// B[k][n]: n=lane&15 (code), k=(lane>>4)*8+j. quad0: eh, quad1: el, quad2: eh,
// quad3: {e2h, e2l, 0x6}.
__global__ void prep(const float* __restrict__ cb, float* __restrict__ e2f,
                     unsigned short* __restrict__ wsB, float* __restrict__ out_loss) {
    const int tid = blockIdx.x * 256 + threadIdx.x;
    if (tid == 0) *out_loss = 0.0f;
    const int t    = tid >> 6;
    const int lane = tid & 63;
    const int quad = lane >> 4;
    const int colc = lane & 15;
    const int n    = t * 16 + colc;
    float row[DDIM];
    #pragma unroll
    for (int j = 0; j < DDIM; ++j) row[j] = cb[n * DDIM + j];
    const float e2 = np_sumsq8(row);
    if (quad == 3) e2f[n] = e2;

    unsigned short sh[8];
    #pragma unroll
    for (int j = 0; j < 8; ++j) {
        const unsigned short eh = f2bf(row[j]);
        const unsigned short el = f2bf(__fsub_rn(row[j], bf2f(eh)));
        sh[j] = (quad == 1) ? el : eh;
    }
    if (quad == 3) {
        const unsigned short e2h = f2bf(e2);
        const unsigned short e2l = f2bf(__fsub_rn(e2, bf2f(e2h)));
        sh[0] = e2h; sh[1] = e2l;
        #pragma unroll
        for (int j = 2; j < 8; ++j) sh[j] = 0;
    }
    unsigned short* dst = wsB + (size_t)(t * 64 + lane) * 8;
    #pragma unroll
    for (int j = 0; j < 8; ++j) dst[j] = sh[j];
}

__global__ __launch_bounds__(BLK, 4) void vq_main(
    const float* __restrict__ z, const float* __restrict__ cb,
    const float* __restrict__ e2f, const unsigned short* __restrict__ wsB,
    float* __restrict__ out_zq, float* __restrict__ out_loss,
    float* __restrict__ out_idx)
{
    __shared__ unsigned short ldsB[NTILES * 64 * 8];   // 32 KB
    __shared__ int            ccnt[BLK];               // 2 KB
    __shared__ unsigned short clist[BLK][CMAX];        // 4 KB
    __shared__ float          wsum[NWAVES];

    const int tid  = threadIdx.x;
    const int wave = tid >> 6;
    const int lane = tid & 63;
    const int quad = lane >> 4;
    const int col  = lane & 15;

    // stage B fragments global -> LDS (32 KB, coalesced uint4, 4 iters @512thr)
    {
        const uint4* src = (const uint4*)wsB;
        uint4* dst = (uint4*)ldsB;
        #pragma unroll
        for (int q = 0; q < 4; ++q)
            dst[tid + q * BLK] = src[tid + q * BLK];
    }
    ccnt[tid] = 0;

    // lane owns point n: fully coalesced loads
    const int n = blockIdx.x * BLK + tid;
    const int b = n >> 16;
    const int s = n & 65535;
    const float* zp = z + (size_t)b * B_STRIDE + s;
    float zv[DDIM];
    #pragma unroll
    for (int j = 0; j < DDIM; ++j) zv[j] = zp[(size_t)j * CH_STRIDE];
    const float z2 = np_sumsq8(zv);

    // wave-wide z2 max -> eps (validated constants)
    float zmax = z2;
    #pragma unroll
    for (int mk = 1; mk <= 32; mk <<= 1) zmax = fmaxf(zmax, __shfl_xor(zmax, mk, 64));
    const float eps = zmax * 6e-7f + 3e-6f;

    // pre-pack own point's A-material: lo16 = bf16(-2*zh), hi16 = bf16(-2*zl)
    unsigned pkz[8];
    #pragma unroll
    for (int j = 0; j < 8; ++j) {
        const unsigned short hh = f2bf(zv[j]);
        const float zh = bf2f(hh);
        const float zl = __fsub_rn(zv[j], zh);        // exact
        const unsigned short ah = f2bf(-2.0f * zh);   // exact
        const unsigned short al = f2bf(-2.0f * zl);
        pkz[j] = (unsigned)ah | ((unsigned)al << 16);
    }

    // afrag_q at lane (col,quad): A[m=col][k=quad*8+j] from owner lane q*16+col.
    // quad0/1: -2zh, quad2: -2zl, quad3: {1,1,0..} (validated)
    bf8 af0, af1, af2, af3;
#define MK_AFRAG(AF, Q)                                                        \
    {                                                                          \
        const int srcl = (Q)*16 + col;                                         \
        _Pragma("unroll")                                                      \
        for (int j = 0; j < 8; ++j) {                                          \
            const unsigned w = (unsigned)__shfl((int)pkz[j], srcl, 64);        \
            const unsigned us = (quad == 2) ? (w >> 16) : (w & 0xFFFFu);       \
            AF[j] = (short)us;                                                 \
        }                                                                      \
        if (quad == 3) AF = (bf8){(short)0x3F80, (short)0x3F80, 0, 0, 0, 0, 0, 0}; \
    }
    MK_AFRAG(af0, 0) MK_AFRAG(af1, 1) MK_AFRAG(af2, 2) MK_AFRAG(af3, 3)

    __syncthreads();   // ldsB staged by all waves -> needed (kept)

    const bf8* __restrict__ Bp = (const bf8*)ldsB;   // ds_read_b128 per tile

    // ---- pass 1: approx min per point (4 ptiles x 4 regs) ----
    f4 mn0 = (f4){FLT_BIG, FLT_BIG, FLT_BIG, FLT_BIG};
    f4 mn1 = mn0, mn2 = mn0, mn3 = mn0;
    #pragma unroll 4
    for (int t = 0; t < NTILES; ++t) {
        const bf8 bfrag = Bp[t * 64 + lane];
        f4 zero = (f4){0.0f, 0.0f, 0.0f, 0.0f};
        const f4 a0 = __builtin_amdgcn_mfma_f32_16x16x32_bf16(af0, bfrag, zero, 0, 0, 0);
        const f4 a1 = __builtin_amdgcn_mfma_f32_16x16x32_bf16(af1, bfrag, zero, 0, 0, 0);
        const f4 a2 = __builtin_amdgcn_mfma_f32_16x16x32_bf16(af2, bfrag, zero, 0, 0, 0);
        const f4 a3 = __builtin_amdgcn_mfma_f32_16x16x32_bf16(af3, bfrag, zero, 0, 0, 0);
        #pragma unroll
        for (int r = 0; r < 4; ++r) {
            mn0[r] = fminf(mn0[r], a0[r]); mn1[r] = fminf(mn1[r], a1[r]);
            mn2[r] = fminf(mn2[r], a2[r]); mn3[r] = fminf(mn3[r], a3[r]);
        }
    }
    // min across the 16 cols (xor bits 0..3), then add eps -> thresholds
    #pragma unroll
    for (int mk = 1; mk <= 8; mk <<= 1) {
        #pragma unroll
        for (int r = 0; r < 4; ++r) {
            mn0[r] = fminf(mn0[r], __shfl_xor(mn0[r], mk, 64));
            mn1[r] = fminf(mn1[r], __shfl_xor(mn1[r], mk, 64));
            mn2[r] = fminf(mn2[r], __shfl_xor(mn2[r], mk, 64));
            mn3[r] = fminf(mn3[r], __shfl_xor(mn3[r], mk, 64));
        }
    }
    #pragma unroll
    for (int r = 0; r < 4; ++r) {
        mn0[r] += eps; mn1[r] += eps; mn2[r] += eps; mn3[r] += eps;
    }

    // ---- pass 2: identical accs; predicated push (rarely taken) ----
    // C layout: point-in-block = wave*64 + Q*16 + quad*4 + r, code = t*16 + col
    const int pbase = wave * 64 + quad * 4;
    #pragma unroll 4
    for (int t = 0; t < NTILES; ++t) {
        const bf8 bfrag = Bp[t * 64 + lane];
        f4 zero = (f4){0.0f, 0.0f, 0.0f, 0.0f};
        const f4 a0 = __builtin_amdgcn_mfma_f32_16x16x32_bf16(af0, bfrag, zero, 0, 0, 0);
        const f4 a1 = __builtin_amdgcn_mfma_f32_16x16x32_bf16(af1, bfrag, zero, 0, 0, 0);
        const f4 a2 = __builtin_amdgcn_mfma_f32_16x16x32_bf16(af2, bfrag, zero, 0, 0, 0);
        const f4 a3 = __builtin_amdgcn_mfma_f32_16x16x32_bf16(af3, bfrag, zero, 0, 0, 0);
        const unsigned short code = (unsigned short)(t * 16 + col);
#define PUSH(AQ, MQ, Q)                                                        \
    {                                                                          \
        const bool c0 = AQ[0] <= MQ[0], c1 = AQ[1] <= MQ[1];                   \
        const bool c2 = AQ[2] <= MQ[2], c3 = AQ[3] <= MQ[3];                   \
        if (c0 | c1 | c2 | c3) {                                               \
            const int pt = pbase + (Q)*16;                                     \
            if (c0) { int p = atomicAdd(&ccnt[pt + 0], 1); if (p < CMAX) clist[pt + 0][p] = code; } \
            if (c1) { int p = atomicAdd(&ccnt[pt + 1], 1); if (p < CMAX) clist[pt + 1][p] = code; } \
            if (c2) { int p = atomicAdd(&ccnt[pt + 2], 1); if (p < CMAX) clist[pt + 2][p] = code; } \
            if (c3) { int p = atomicAdd(&ccnt[pt + 3], 1); if (p < CMAX) clist[pt + 3][p] = code; } \
        }                                                                      \
    }
        PUSH(a0, mn0, 0) PUSH(a1, mn1, 1) PUSH(a2, mn2, 2) PUSH(a3, mn3, 3)
    }

    // ccnt/clist for this wave's 64 points is written and read ONLY by this
    // wave -> no block barrier; drain this wave's LDS ops (writes + atomics).
    asm volatile("s_waitcnt lgkmcnt(0)" ::: "memory");

    // ---- phase C: every lane resolves its own point np-exactly ----
    const int cnt = ccnt[tid];
    int bidx;
    if (cnt == 1) {
        // eps guarantee: candidate set contains np's argmin; singleton => done
        bidx = clist[tid][0];
    } else if (cnt <= CMAX) {
        float best = FLT_BIG; bidx = 0;
        for (int i = 0; i < cnt; ++i) {
            const int k = clist[tid][i];
            const float d = np_dist(cb, e2f, k, zv, z2);
            // order-independent np first-min
            if (d < best || (d == best && k < bidx)) { best = d; bidx = k; }
        }
    } else {  // overflow fallback: full exact scan (correctness net)
        float best = FLT_BIG; bidx = 0;
        for (int k = 0; k < KCODES; ++k) {
            const float d = np_dist(cb, e2f, k, zv, z2);
            if (d < best) { best = d; bidx = k; }
        }
    }
    out_idx[n] = (float)bidx;

    const float* cw = cb + (size_t)bidx * DDIM;
    float* op = out_zq + (size_t)b * B_STRIDE + s;
    float lsum = 0.0f;
    #pragma unroll
    for (int j = 0; j < DDIM; ++j) {
        const float zq = cw[j];
        const float t  = __fsub_rn(zq, zv[j]);            // np: z_q - z
        op[(size_t)j * CH_STRIDE] = __fadd_rn(zv[j], t);  // np: z + (z_q - z)
        lsum = __fmaf_rn(t, t, lsum);                     // loss (2% tol)
    }

    // loss: wave butterfly -> LDS wsum -> one atomic per BLOCK (R12 path;
    // R13's per-wave same-address atomics serialized ~26cyc each = +90us)
    #pragma unroll
    for (int off = 32; off > 0; off >>= 1) lsum += __shfl_down(lsum, off, 64);
    if (lane == 0) wsum[wave] = lsum;
    __syncthreads();
    if (tid == 0) {
        float bs = 0.0f;
        #pragma unroll
        for (int w = 0; w < NWAVES; ++w) bs += wsum[w];
        // vq_loss = codebk + BETA*commit = 1.25 * mean((z_q - z)^2)
        atomicAdd(out_loss, bs * (1.25f / 4194304.0f));
    }
}

extern "C" void kernel_launch(void* const* d_in, const int* in_sizes, int n_in,
                              void* d_out, int out_size, void* d_ws, size_t ws_size,
                              hipStream_t stream) {
    const float* z  = (const float*)d_in[0];
    const float* cb = (const float*)d_in[1];
    float* out      = (float*)d_out;
    float* out_zq   = out;                    // 4194304 elems
    float* out_loss = out + 4194304;          // 1 elem
    float* out_idx  = out + 4194305;          // 524288 elems (as float values)
    float* e2f            = (float*)d_ws;                           // 512 f32
    unsigned short* wsB   = (unsigned short*)((char*)d_ws + 2048);  // 32KB frags

    prep<<<8, 256, 0, stream>>>(cb, e2f, wsB, out_loss);
    vq_main<<<NPTS / BLK, BLK, 0, stream>>>(z, cb, e2f, wsB,
                                            out_zq, out_loss, out_idx);
}